// Round 9
// baseline (611.879 us; speedup 1.0000x reference)
//
#include <hip/hip_runtime.h>
#include <hip/hip_bf16.h>

#define N_NODES 50000
#define N_EDGES 800000

typedef short  short8  __attribute__((ext_vector_type(8)));
typedef float  floatx4 __attribute__((ext_vector_type(4)));

__device__ __forceinline__ short f2bf(float f) {
    union { __hip_bfloat16 h; short s; } u;
    u.h = __float2bfloat16(f);
    return u.s;
}
__device__ __forceinline__ float2 upk(unsigned v) {
    union { float f; unsigned u; } a, b;
    a.u = v << 16; b.u = v & 0xffff0000u;
    return make_float2(a.f, b.f);
}
__device__ __forceinline__ unsigned packbf(float lo, float hi) {
    return ((unsigned)(unsigned short)f2bf(hi) << 16) | (unsigned short)f2bf(lo);
}

__device__ __forceinline__ void gld_lds16(const short* g, short* l) {
    __builtin_amdgcn_global_load_lds(
        (const __attribute__((address_space(1))) int*)g,
        (__attribute__((address_space(3))) int*)l, 16, 0, 0);
}

// ---------------------------------------------------------------- CSR build
__global__ void k_deg(const int* __restrict__ dst, int* __restrict__ deg) {
    int e = blockIdx.x * 256 + threadIdx.x;
    if (e < N_EDGES) atomicAdd(&deg[dst[e]], 1);
}

// phase 1: per-block (1024) sums + dinv
__global__ __launch_bounds__(1024) void k_scan1(const int* __restrict__ deg,
                                                int* __restrict__ bsum,
                                                float* __restrict__ dinv) {
    __shared__ int ws[16];
    int b = blockIdx.x, t = threadIdx.x, i = b * 1024 + t;
    int lane = t & 63, wid = t >> 6;
    int v = (i < N_NODES) ? deg[i] : 0;
    if (i < N_NODES) dinv[i] = 1.0f / fmaxf((float)v, 1.0f);
    int x = v;
    #pragma unroll
    for (int off = 1; off < 64; off <<= 1) x += __shfl_xor(x, off, 64);
    if (lane == 0) ws[wid] = x;
    __syncthreads();
    if (t == 0) {
        int s = 0;
        #pragma unroll
        for (int k = 0; k < 16; ++k) s += ws[k];
        bsum[b] = s;
    }
}

// phase 2: exclusive scan of 49 block sums (single wave)
__global__ void k_scan2(const int* __restrict__ bsum, int* __restrict__ boff) {
    int lane = threadIdx.x;
    int v = (lane < 49) ? bsum[lane] : 0;
    int x = v;
    #pragma unroll
    for (int off = 1; off < 64; off <<= 1) {
        int y = __shfl_up(x, off, 64);
        if (lane >= off) x += y;
    }
    if (lane < 49) boff[lane] = x - v;
}

// phase 3: per-block rescan -> rowptr / cursor
__global__ __launch_bounds__(1024) void k_scan3(const int* __restrict__ deg,
                                                const int* __restrict__ boff,
                                                int* __restrict__ rowptr,
                                                int* __restrict__ cursor) {
    __shared__ int ws[16];
    int b = blockIdx.x, t = threadIdx.x, i = b * 1024 + t;
    int lane = t & 63, wid = t >> 6;
    int v = (i < N_NODES) ? deg[i] : 0;
    int x = v;
    #pragma unroll
    for (int off = 1; off < 64; off <<= 1) {
        int y = __shfl_up(x, off, 64);
        if (lane >= off) x += y;
    }
    if (lane == 63) ws[wid] = x;
    __syncthreads();
    if (wid == 0) {
        int s = (lane < 16) ? ws[lane] : 0;
        #pragma unroll
        for (int off = 1; off < 16; off <<= 1) {
            int y = __shfl_up(s, off, 64);
            if (lane >= off) s += y;
        }
        if (lane < 16) ws[lane] = s;
    }
    __syncthreads();
    int waveOff = (wid == 0) ? 0 : ws[wid - 1];
    int incl = x + waveOff + boff[b];
    if (i < N_NODES) { rowptr[i + 1] = incl; cursor[i] = incl - v; }
    if (b == 0 && t == 0) rowptr[0] = 0;
}

__global__ void k_fill(const int* __restrict__ src, const int* __restrict__ dst,
                       int* __restrict__ cursor, int* __restrict__ col) {
    int e = blockIdx.x * 256 + threadIdx.x;
    if (e < N_EDGES) {
        int d = dst[e];
        int p = atomicAdd(&cursor[d], 1);
        col[p] = src[e];
    }
}

// ------------------------------------------- fused bf16 conversions
// blocks [0,6250): feat -> Abf cols 0..127; blocks [6250,7274): weights
__global__ void k_cvt(const float* __restrict__ feat,
                      const float* __restrict__ W1s, const float* __restrict__ W1n,
                      const float* __restrict__ W2s, const float* __restrict__ W2n,
                      short* __restrict__ Abf, short* __restrict__ W1T,
                      short* __restrict__ W2T) {
    int bb = blockIdx.x, t = threadIdx.x;
    if (bb < 6250) {
        int idx = bb * 256 + t;
        if (idx >= N_NODES * 32) return;
        int n = idx >> 5, c = (idx & 31) * 4;
        float4 v = *(const float4*)(feat + (size_t)n * 128 + c);
        *(short4*)(Abf + (size_t)n * 256 + c) =
            make_short4(f2bf(v.x), f2bf(v.y), f2bf(v.z), f2bf(v.w));
    } else {
        int idx = (bb - 6250) * 256 + t;
        if (idx < 512 * 256) {
            int n = idx >> 8, k = idx & 255;
            float v = (k < 128) ? W1s[(size_t)k * 512 + n]
                                : W1n[(size_t)(k - 128) * 512 + n];
            W1T[idx] = f2bf(v);
        } else {
            int j = idx - 512 * 256;
            int n = j >> 9, k = j & 511;
            float v = (n < 128) ? W2s[(size_t)k * 128 + n]
                                : W2n[(size_t)k * 128 + (n - 128)];
            W2T[j] = f2bf(v);
        }
    }
}

// -------- wave-per-node gather core: scalar-base (readlane) row loads,
// 16-deep pipeline.
template<int STRIDE>
__device__ __forceinline__ float2 wave_gather(
    const unsigned* __restrict__ U, const int* __restrict__ col,
    int s, int e, int lane) {
    float ax = 0.f, ay = 0.f;
    for (int base = s; base < e; base += 64) {
        int cnt = e - base; if (cnt > 64) cnt = 64;
        int myc = (base + lane < e) ? col[base + lane] : 0;
        int j = 0;
        for (; j + 16 <= cnt; j += 16) {
            unsigned v[16];
            #pragma unroll
            for (int u = 0; u < 16; ++u) {
                int c = __builtin_amdgcn_readlane(myc, j + u);
                v[u] = U[(size_t)c * STRIDE + lane];
            }
            #pragma unroll
            for (int u = 0; u < 16; ++u) {
                float2 f = upk(v[u]); ax += f.x; ay += f.y;
            }
        }
        for (; j + 8 <= cnt; j += 8) {
            unsigned v[8];
            #pragma unroll
            for (int u = 0; u < 8; ++u) {
                int c = __builtin_amdgcn_readlane(myc, j + u);
                v[u] = U[(size_t)c * STRIDE + lane];
            }
            #pragma unroll
            for (int u = 0; u < 8; ++u) {
                float2 f = upk(v[u]); ax += f.x; ay += f.y;
            }
        }
        if (j < cnt) {
            unsigned v[8];
            int m = cnt - j;
            #pragma unroll
            for (int u = 0; u < 8; ++u) {
                if (u < m) {
                    int c = __builtin_amdgcn_readlane(myc, j + u);
                    v[u] = U[(size_t)c * STRIDE + lane];
                }
            }
            #pragma unroll
            for (int u = 0; u < 8; ++u) {
                if (u < m) { float2 f = upk(v[u]); ax += f.x; ay += f.y; }
            }
        }
    }
    return make_float2(ax, ay);
}

// XCD-restricted grid: launch 12504 blocks; only blockIdx%8<2 survive
// (heuristically 2 XCDs -> per-XCD L2 fill volume /4). Each surviving
// block handles 16 nodes (4 per wave).
#define GATHER_GRID 12504

// ---------------------------------------------- aggregation 1 (bf16 gather)
__global__ __launch_bounds__(256) void k_agg(
    const unsigned* __restrict__ Au, const int* __restrict__ rowptr,
    const int* __restrict__ col, const float* __restrict__ dinv,
    unsigned* __restrict__ Aw) {
    int b = blockIdx.x;
    if ((b & 7) >= 2) return;
    int sb = (b >> 3) * 2 + (b & 7);
    if (sb >= 3125) return;
    int t = threadIdx.x, lane = t & 63, w = t >> 6;
    #pragma unroll
    for (int r = 0; r < 4; ++r) {
        int n = sb * 16 + w * 4 + r;
        int s = rowptr[n], e = rowptr[n + 1];
        float2 a = wave_gather<128>(Au, col, s, e, lane);
        float dv = dinv[n];
        Aw[(size_t)n * 128 + 64 + lane] = packbf(a.x * dv, a.y * dv);
    }
}

// --------------------- aggregation 2 + bias/relu + MLP + softmax (fused)
__global__ __launch_bounds__(256) void k_aggmlp(
    const unsigned* __restrict__ Yu, const int* __restrict__ rowptr,
    const int* __restrict__ col, const float* __restrict__ dinv,
    const float* __restrict__ z, const float* __restrict__ b2,
    const float* __restrict__ Wp1, const float* __restrict__ bp1,
    const float* __restrict__ Wp2, const float* __restrict__ bp2,
    float* __restrict__ out) {
    __shared__ float h2sh[4][128];
    __shared__ float xsh[4][32];
    int b = blockIdx.x;
    if ((b & 7) >= 2) return;
    int sb = (b >> 3) * 2 + (b & 7);
    if (sb >= 3125) return;
    int t = threadIdx.x, lane = t & 63, w = t >> 6;
    for (int r = 0; r < 4; ++r) {
        int n = sb * 16 + w * 4 + r;
        int s = rowptr[n], e = rowptr[n + 1];
        float2 a = wave_gather<64>(Yu, col, s, e, lane);
        float dv = dinv[n];
        float2 zv = *(const float2*)(z + (size_t)n * 128 + 2 * lane);
        float2 bb = *(const float2*)(b2 + 2 * lane);
        h2sh[w][2 * lane]     = fmaxf(zv.x + a.x * dv + bb.x, 0.f);
        h2sh[w][2 * lane + 1] = fmaxf(zv.y + a.y * dv + bb.y, 0.f);
        __syncthreads();
        int j = lane & 31, half = lane >> 5;
        float p = 0.f;
        #pragma unroll
        for (int k2 = 0; k2 < 64; ++k2) {
            int k = half * 64 + k2;
            p += h2sh[w][k] * Wp1[k * 32 + j];
        }
        p += __shfl_xor(p, 32, 64);
        if (half == 0) xsh[w][j] = fmaxf(p + bp1[j], 0.f);
        __syncthreads();
        if (lane < 8) {
            float lg = bp2[lane];
            #pragma unroll
            for (int jj = 0; jj < 32; ++jj)
                lg += xsh[w][jj] * Wp2[jj * 8 + lane];
            float mx = lg;
            mx = fmaxf(mx, __shfl_xor(mx, 1, 64));
            mx = fmaxf(mx, __shfl_xor(mx, 2, 64));
            mx = fmaxf(mx, __shfl_xor(mx, 4, 64));
            float ev = expf(lg - mx);
            float sm = ev;
            sm += __shfl_xor(sm, 1, 64);
            sm += __shfl_xor(sm, 2, 64);
            sm += __shfl_xor(sm, 4, 64);
            out[(size_t)n * 8 + lane] = ev / sm;
        }
        __syncthreads();
    }
}

// ------------------------------------------------------- MFMA bf16 GEMM
template<int K, int N, bool EPI1>
__global__ __launch_bounds__(256) void k_gemm_mfma(
    const short* __restrict__ A, const short* __restrict__ BT,
    const float* __restrict__ bias, short* __restrict__ Obf,
    float* __restrict__ Of0) {
    __shared__ short sA[128 * 32];
    __shared__ short sB[128 * 32];
    const int t = threadIdx.x;
    const int lane = t & 63;
    const int w = t >> 6;
    const int mBase = blockIdx.x * 128;
    const int nBase = blockIdx.y * 128;
    const int mOff = (w & 1) * 64;
    const int nOff = (w >> 1) * 64;

    floatx4 zero4 = {0.f, 0.f, 0.f, 0.f};
    floatx4 acc[4][4];
    #pragma unroll
    for (int i = 0; i < 4; ++i)
        #pragma unroll
        for (int j = 0; j < 4; ++j) acc[i][j] = zero4;

    const int rL = lane >> 2;
    const int cg = (((lane & 3) ^ ((lane >> 3) & 3))) * 8;
    const int rA = w * 32 + rL;
    const long gA0 = (long)min(mBase + rA,      N_NODES - 1) * K + cg;
    const long gA1 = (long)min(mBase + rA + 16, N_NODES - 1) * K + cg;
    const long gB0 = (long)(nBase + rA)      * K + cg;
    const long gB1 = (long)(nBase + rA + 16) * K + cg;
    short* lA0 = sA + (w * 32) * 32;
    short* lA1 = sA + (w * 32 + 16) * 32;
    short* lB0 = sB + (w * 32) * 32;
    short* lB1 = sB + (w * 32 + 16) * 32;

    const int fr = lane & 15;
    const int csel = (((lane >> 4) ^ ((lane >> 1) & 3))) * 8;

    for (int kt = 0; kt < K / 32; ++kt) {
        const int k0 = kt * 32;
        __syncthreads();
        gld_lds16(A + gA0 + k0, lA0);
        gld_lds16(A + gA1 + k0, lA1);
        gld_lds16(BT + gB0 + k0, lB0);
        gld_lds16(BT + gB1 + k0, lB1);
        __syncthreads();
        short8 af[4], bf[4];
        #pragma unroll
        for (int i = 0; i < 4; ++i) {
            af[i] = *(const short8*)(sA + (mOff + i * 16 + fr) * 32 + csel);
            bf[i] = *(const short8*)(sB + (nOff + i * 16 + fr) * 32 + csel);
        }
        #pragma unroll
        for (int mi = 0; mi < 4; ++mi)
            #pragma unroll
            for (int ni = 0; ni < 4; ++ni)
                acc[mi][ni] = __builtin_amdgcn_mfma_f32_16x16x32_bf16(
                    af[mi], bf[ni], acc[mi][ni], 0, 0, 0);
    }

    const int cn = lane & 15;
    const int cm = (lane >> 4) * 4;
    #pragma unroll
    for (int ni = 0; ni < 4; ++ni) {
        const int n = nBase + nOff + ni * 16 + cn;
        float bv = 0.f;
        if constexpr (EPI1) bv = bias[n];
        #pragma unroll
        for (int mi = 0; mi < 4; ++mi) {
            #pragma unroll
            for (int r = 0; r < 4; ++r) {
                const int m = mBase + mOff + mi * 16 + cm + r;
                if (m < N_NODES) {
                    if constexpr (EPI1) {
                        Obf[(size_t)m * N + n] = f2bf(fmaxf(acc[mi][ni][r] + bv, 0.f));
                    } else {
                        if (n < 128) Of0[(size_t)m * 128 + n] = acc[mi][ni][r];
                        else         Obf[(size_t)m * 128 + (n - 128)] = f2bf(acc[mi][ni][r]);
                    }
                }
            }
        }
    }
}

// ---------------------------------------------------------------- launch
extern "C" void kernel_launch(void* const* d_in, const int* in_sizes, int n_in,
                              void* d_out, int out_size, void* d_ws, size_t ws_size,
                              hipStream_t stream) {
    const float* feat   = (const float*)d_in[0];
    const int*   src    = (const int*)d_in[1];
    const int*   dst    = (const int*)d_in[2];
    const float* W1s    = (const float*)d_in[3];
    const float* W1n    = (const float*)d_in[4];
    const float* b1     = (const float*)d_in[5];
    const float* W2s    = (const float*)d_in[6];
    const float* W2n    = (const float*)d_in[7];
    const float* b2     = (const float*)d_in[8];
    const float* Wp1    = (const float*)d_in[9];
    const float* bp1    = (const float*)d_in[10];
    const float* Wp2    = (const float*)d_in[11];
    const float* bp2    = (const float*)d_in[12];
    float* out = (float*)d_out;

    char* w = (char*)d_ws;
    size_t off = 0;
    auto alloc = [&](size_t bytes) { char* p = w + off; off += (bytes + 255) & ~(size_t)255; return p; };
    int*   deg    = (int*)alloc(N_NODES * 4);
    int*   rowptr = (int*)alloc((N_NODES + 1) * 4);
    int*   cursor = (int*)alloc(N_NODES * 4);
    int*   col    = (int*)alloc(N_EDGES * 4);
    float* dinv   = (float*)alloc(N_NODES * 4);
    int*   bsum   = (int*)alloc(64 * 4);
    int*   boff   = (int*)alloc(64 * 4);
    short* Abf    = (short*)alloc((size_t)N_NODES * 256 * 2);   // [feat|agg1] bf16
    short* W1T    = (short*)alloc((size_t)512 * 256 * 2);
    short* W2T    = (short*)alloc((size_t)256 * 512 * 2);
    short* h1bf   = (short*)alloc((size_t)N_NODES * 512 * 2);
    float* z      = (float*)alloc((size_t)N_NODES * 128 * 4);
    short* y1bf   = (short*)alloc((size_t)N_NODES * 128 * 2);

    hipMemsetAsync(deg, 0, N_NODES * 4, stream);
    k_deg<<<N_EDGES / 256, 256, 0, stream>>>(dst, deg);
    k_scan1<<<49, 1024, 0, stream>>>(deg, bsum, dinv);
    k_scan2<<<1, 64, 0, stream>>>(bsum, boff);
    k_scan3<<<49, 1024, 0, stream>>>(deg, boff, rowptr, cursor);
    k_fill<<<N_EDGES / 256, 256, 0, stream>>>(src, dst, cursor, col);
    k_cvt<<<7274, 256, 0, stream>>>(feat, W1s, W1n, W2s, W2n, Abf, W1T, W2T);
    k_agg<<<GATHER_GRID, 256, 0, stream>>>((const unsigned*)Abf, rowptr, col, dinv, (unsigned*)Abf);
    dim3 g1((N_NODES + 127) / 128, 4);
    k_gemm_mfma<256, 512, true><<<g1, 256, 0, stream>>>(Abf, W1T, b1, h1bf, nullptr);
    dim3 g2((N_NODES + 127) / 128, 2);
    k_gemm_mfma<512, 256, false><<<g2, 256, 0, stream>>>(h1bf, W2T, nullptr, y1bf, z);
    k_aggmlp<<<GATHER_GRID, 256, 0, stream>>>((const unsigned*)y1bf, rowptr, col, dinv, z, b2,
                                              Wp1, bp1, Wp2, bp2, out);
}

// Round 10
// 399.623 us; speedup vs baseline: 1.5311x; 1.5311x over previous
//
#include <hip/hip_runtime.h>
#include <hip/hip_bf16.h>

#define N_NODES 50000
#define N_EDGES 800000

typedef short  short8  __attribute__((ext_vector_type(8)));
typedef float  floatx4 __attribute__((ext_vector_type(4)));

__device__ __forceinline__ short f2bf(float f) {
    union { __hip_bfloat16 h; short s; } u;
    u.h = __float2bfloat16(f);
    return u.s;
}
__device__ __forceinline__ float2 upk(unsigned v) {
    union { float f; unsigned u; } a, b;
    a.u = v << 16; b.u = v & 0xffff0000u;
    return make_float2(a.f, b.f);
}
__device__ __forceinline__ unsigned packbf(float lo, float hi) {
    return ((unsigned)(unsigned short)f2bf(hi) << 16) | (unsigned short)f2bf(lo);
}

__device__ __forceinline__ void gld_lds16(const short* g, short* l) {
    __builtin_amdgcn_global_load_lds(
        (const __attribute__((address_space(1))) int*)g,
        (__attribute__((address_space(3))) int*)l, 16, 0, 0);
}

// ---------------------------------------------------------------- CSR build
__global__ void k_deg(const int* __restrict__ dst, int* __restrict__ deg) {
    int e = blockIdx.x * 256 + threadIdx.x;
    if (e < N_EDGES) atomicAdd(&deg[dst[e]], 1);
}

__global__ __launch_bounds__(1024) void k_scan1(const int* __restrict__ deg,
                                                int* __restrict__ bsum,
                                                float* __restrict__ dinv) {
    __shared__ int ws[16];
    int b = blockIdx.x, t = threadIdx.x, i = b * 1024 + t;
    int lane = t & 63, wid = t >> 6;
    int v = (i < N_NODES) ? deg[i] : 0;
    if (i < N_NODES) dinv[i] = 1.0f / fmaxf((float)v, 1.0f);
    int x = v;
    #pragma unroll
    for (int off = 1; off < 64; off <<= 1) x += __shfl_xor(x, off, 64);
    if (lane == 0) ws[wid] = x;
    __syncthreads();
    if (t == 0) {
        int s = 0;
        #pragma unroll
        for (int k = 0; k < 16; ++k) s += ws[k];
        bsum[b] = s;
    }
}

__global__ void k_scan2(const int* __restrict__ bsum, int* __restrict__ boff) {
    int lane = threadIdx.x;
    int v = (lane < 49) ? bsum[lane] : 0;
    int x = v;
    #pragma unroll
    for (int off = 1; off < 64; off <<= 1) {
        int y = __shfl_up(x, off, 64);
        if (lane >= off) x += y;
    }
    if (lane < 49) boff[lane] = x - v;
}

__global__ __launch_bounds__(1024) void k_scan3(const int* __restrict__ deg,
                                                const int* __restrict__ boff,
                                                int* __restrict__ rowptr,
                                                int* __restrict__ cursor) {
    __shared__ int ws[16];
    int b = blockIdx.x, t = threadIdx.x, i = b * 1024 + t;
    int lane = t & 63, wid = t >> 6;
    int v = (i < N_NODES) ? deg[i] : 0;
    int x = v;
    #pragma unroll
    for (int off = 1; off < 64; off <<= 1) {
        int y = __shfl_up(x, off, 64);
        if (lane >= off) x += y;
    }
    if (lane == 63) ws[wid] = x;
    __syncthreads();
    if (wid == 0) {
        int s = (lane < 16) ? ws[lane] : 0;
        #pragma unroll
        for (int off = 1; off < 16; off <<= 1) {
            int y = __shfl_up(s, off, 64);
            if (lane >= off) s += y;
        }
        if (lane < 16) ws[lane] = s;
    }
    __syncthreads();
    int waveOff = (wid == 0) ? 0 : ws[wid - 1];
    int incl = x + waveOff + boff[b];
    if (i < N_NODES) { rowptr[i + 1] = incl; cursor[i] = incl - v; }
    if (b == 0 && t == 0) rowptr[0] = 0;
}

__global__ void k_fill(const int* __restrict__ src, const int* __restrict__ dst,
                       int* __restrict__ cursor, int* __restrict__ col) {
    int e = blockIdx.x * 256 + threadIdx.x;
    if (e < N_EDGES) {
        int d = dst[e];
        int p = atomicAdd(&cursor[d], 1);
        col[p] = src[e];
    }
}

// ------------------------------------------- fused bf16 conversions
__global__ void k_cvt(const float* __restrict__ feat,
                      const float* __restrict__ W1s, const float* __restrict__ W1n,
                      const float* __restrict__ W2s, const float* __restrict__ W2n,
                      short* __restrict__ Abf, short* __restrict__ W1T,
                      short* __restrict__ W2T) {
    int bb = blockIdx.x, t = threadIdx.x;
    if (bb < 6250) {
        int idx = bb * 256 + t;
        if (idx >= N_NODES * 32) return;
        int n = idx >> 5, c = (idx & 31) * 4;
        float4 v = *(const float4*)(feat + (size_t)n * 128 + c);
        *(short4*)(Abf + (size_t)n * 256 + c) =
            make_short4(f2bf(v.x), f2bf(v.y), f2bf(v.z), f2bf(v.w));
    } else {
        int idx = (bb - 6250) * 256 + t;
        if (idx < 512 * 256) {
            int n = idx >> 8, k = idx & 255;
            float v = (k < 128) ? W1s[(size_t)k * 512 + n]
                                : W1n[(size_t)(k - 128) * 512 + n];
            W1T[idx] = f2bf(v);
        } else {
            int j = idx - 512 * 256;
            int n = j >> 9, k = j & 511;
            float v = (n < 128) ? W2s[(size_t)k * 128 + n]
                                : W2n[(size_t)k * 128 + (n - 128)];
            W2T[j] = f2bf(v);
        }
    }
}

// -------- gather core: 1 node per wave, uint2/lane, 2 edges per load instr
// (lanes 0-31 = edge 2j, lanes 32-63 = edge 2j+1). ds_bpermute broadcast of
// indices; cross-half reduce at the end. a[4] = channels 4sl..4sl+3.
template<int W, int STRIDE>
__device__ __forceinline__ void gchunk(const unsigned* __restrict__ U,
                                       int myc, int j, int sub, int voff,
                                       float a[4]) {
    uint2 v[W];
    #pragma unroll
    for (int u = 0; u < W; ++u) {
        int c = __shfl(myc, 2 * (j + u) + sub, 64);
        v[u] = *(const uint2*)(U + (size_t)c * STRIDE + voff);
    }
    #pragma unroll
    for (int u = 0; u < W; ++u) {
        float2 f0 = upk(v[u].x), f1 = upk(v[u].y);
        a[0] += f0.x; a[1] += f0.y; a[2] += f1.x; a[3] += f1.y;
    }
}

template<int STRIDE>
__device__ __forceinline__ void wave_gather2e(
    const unsigned* __restrict__ U, const int* __restrict__ col,
    int s, int e, int lane, float a[4]) {
    const int sub = lane >> 5;
    const int voff = (lane & 31) * 2;
    a[0] = a[1] = a[2] = a[3] = 0.f;
    const int deg = e - s;
    for (int base = 0; base < deg; base += 64) {
        int idx = s + base + lane; if (idx >= e) idx = e - 1;
        int myc = col[idx];
        int lim = deg - base; if (lim > 64) lim = 64;
        int pf = lim >> 1;   // full pairs
        int j = 0;
        for (; j + 16 <= pf; j += 16) gchunk<16, STRIDE>(U, myc, j, sub, voff, a);
        for (; j + 8 <= pf; j += 8)   gchunk<8,  STRIDE>(U, myc, j, sub, voff, a);
        for (; j + 4 <= pf; j += 4)   gchunk<4,  STRIDE>(U, myc, j, sub, voff, a);
        for (; j < pf; ++j)           gchunk<1,  STRIDE>(U, myc, j, sub, voff, a);
        if (lim & 1) {
            int c = __shfl(myc, lim - 1, 64);
            uint2 v = *(const uint2*)(U + (size_t)c * STRIDE + voff);
            if (sub == 0) {
                float2 f0 = upk(v.x), f1 = upk(v.y);
                a[0] += f0.x; a[1] += f0.y; a[2] += f1.x; a[3] += f1.y;
            }
        }
    }
    #pragma unroll
    for (int k = 0; k < 4; ++k) a[k] += __shfl_xor(a[k], 32, 64);
}

// ---------------------------------------------- aggregation 1 (bf16 gather)
__global__ __launch_bounds__(256) void k_agg(
    const unsigned* __restrict__ Au, const int* __restrict__ rowptr,
    const int* __restrict__ col, const float* __restrict__ dinv,
    unsigned* __restrict__ Aw) {
    int t = threadIdx.x, lane = t & 63, w = t >> 6;
    int n = blockIdx.x * 4 + w;
    int s = rowptr[n], e = rowptr[n + 1];
    float a[4];
    wave_gather2e<128>(Au, col, s, e, lane, a);
    if (lane < 32) {
        float dv = dinv[n];
        uint2 o;
        o.x = packbf(a[0] * dv, a[1] * dv);
        o.y = packbf(a[2] * dv, a[3] * dv);
        *(uint2*)(Aw + (size_t)n * 128 + 64 + lane * 2) = o;
    }
}

// --------------------- aggregation 2 + bias/relu + MLP + softmax (fused)
// barrier-free: all LDS traffic is intra-wave.
__global__ __launch_bounds__(256) void k_aggmlp(
    const unsigned* __restrict__ Yu, const int* __restrict__ rowptr,
    const int* __restrict__ col, const float* __restrict__ dinv,
    const float* __restrict__ z, const float* __restrict__ b2,
    const float* __restrict__ Wp1, const float* __restrict__ bp1,
    const float* __restrict__ Wp2, const float* __restrict__ bp2,
    float* __restrict__ out) {
    __shared__ float h2sh[4][128];
    __shared__ float xsh[4][32];
    int t = threadIdx.x, lane = t & 63, w = t >> 6;
    int n = blockIdx.x * 4 + w;
    int s = rowptr[n], e = rowptr[n + 1];
    float a[4];
    wave_gather2e<64>(Yu, col, s, e, lane, a);
    if (lane < 32) {
        float dv = dinv[n];
        float4 zv = *(const float4*)(z + (size_t)n * 128 + lane * 4);
        float4 bb = *(const float4*)(b2 + lane * 4);
        h2sh[w][lane * 4 + 0] = fmaxf(zv.x + a[0] * dv + bb.x, 0.f);
        h2sh[w][lane * 4 + 1] = fmaxf(zv.y + a[1] * dv + bb.y, 0.f);
        h2sh[w][lane * 4 + 2] = fmaxf(zv.z + a[2] * dv + bb.z, 0.f);
        h2sh[w][lane * 4 + 3] = fmaxf(zv.w + a[3] * dv + bb.w, 0.f);
    }
    // intra-wave: no barrier needed (lockstep)
    int j = lane & 31, half = lane >> 5;
    float p = 0.f;
    #pragma unroll
    for (int k2 = 0; k2 < 64; ++k2) {
        int k = half * 64 + k2;
        p += h2sh[w][k] * Wp1[k * 32 + j];
    }
    p += __shfl_xor(p, 32, 64);
    if (half == 0) xsh[w][j] = fmaxf(p + bp1[j], 0.f);
    if (lane < 8) {
        float lg = bp2[lane];
        #pragma unroll
        for (int jj = 0; jj < 32; ++jj)
            lg += xsh[w][jj] * Wp2[jj * 8 + lane];
        float mx = lg;
        mx = fmaxf(mx, __shfl_xor(mx, 1, 64));
        mx = fmaxf(mx, __shfl_xor(mx, 2, 64));
        mx = fmaxf(mx, __shfl_xor(mx, 4, 64));
        float ev = expf(lg - mx);
        float sm = ev;
        sm += __shfl_xor(sm, 1, 64);
        sm += __shfl_xor(sm, 2, 64);
        sm += __shfl_xor(sm, 4, 64);
        out[(size_t)n * 8 + lane] = ev / sm;
    }
}

// ------------------------------------------------------- MFMA bf16 GEMM
template<int K, int N, bool EPI1>
__global__ __launch_bounds__(256) void k_gemm_mfma(
    const short* __restrict__ A, const short* __restrict__ BT,
    const float* __restrict__ bias, short* __restrict__ Obf,
    float* __restrict__ Of0) {
    __shared__ short sA[128 * 32];
    __shared__ short sB[128 * 32];
    const int t = threadIdx.x;
    const int lane = t & 63;
    const int w = t >> 6;
    const int mBase = blockIdx.x * 128;
    const int nBase = blockIdx.y * 128;
    const int mOff = (w & 1) * 64;
    const int nOff = (w >> 1) * 64;

    floatx4 zero4 = {0.f, 0.f, 0.f, 0.f};
    floatx4 acc[4][4];
    #pragma unroll
    for (int i = 0; i < 4; ++i)
        #pragma unroll
        for (int j = 0; j < 4; ++j) acc[i][j] = zero4;

    const int rL = lane >> 2;
    const int cg = (((lane & 3) ^ ((lane >> 3) & 3))) * 8;
    const int rA = w * 32 + rL;
    const long gA0 = (long)min(mBase + rA,      N_NODES - 1) * K + cg;
    const long gA1 = (long)min(mBase + rA + 16, N_NODES - 1) * K + cg;
    const long gB0 = (long)(nBase + rA)      * K + cg;
    const long gB1 = (long)(nBase + rA + 16) * K + cg;
    short* lA0 = sA + (w * 32) * 32;
    short* lA1 = sA + (w * 32 + 16) * 32;
    short* lB0 = sB + (w * 32) * 32;
    short* lB1 = sB + (w * 32 + 16) * 32;

    const int fr = lane & 15;
    const int csel = (((lane >> 4) ^ ((lane >> 1) & 3))) * 8;

    for (int kt = 0; kt < K / 32; ++kt) {
        const int k0 = kt * 32;
        __syncthreads();
        gld_lds16(A + gA0 + k0, lA0);
        gld_lds16(A + gA1 + k0, lA1);
        gld_lds16(BT + gB0 + k0, lB0);
        gld_lds16(BT + gB1 + k0, lB1);
        __syncthreads();
        short8 af[4], bf[4];
        #pragma unroll
        for (int i = 0; i < 4; ++i) {
            af[i] = *(const short8*)(sA + (mOff + i * 16 + fr) * 32 + csel);
            bf[i] = *(const short8*)(sB + (nOff + i * 16 + fr) * 32 + csel);
        }
        #pragma unroll
        for (int mi = 0; mi < 4; ++mi)
            #pragma unroll
            for (int ni = 0; ni < 4; ++ni)
                acc[mi][ni] = __builtin_amdgcn_mfma_f32_16x16x32_bf16(
                    af[mi], bf[ni], acc[mi][ni], 0, 0, 0);
    }

    const int cn = lane & 15;
    const int cm = (lane >> 4) * 4;
    #pragma unroll
    for (int ni = 0; ni < 4; ++ni) {
        const int n = nBase + nOff + ni * 16 + cn;
        float bv = 0.f;
        if constexpr (EPI1) bv = bias[n];
        #pragma unroll
        for (int mi = 0; mi < 4; ++mi) {
            #pragma unroll
            for (int r = 0; r < 4; ++r) {
                const int m = mBase + mOff + mi * 16 + cm + r;
                if (m < N_NODES) {
                    if constexpr (EPI1) {
                        Obf[(size_t)m * N + n] = f2bf(fmaxf(acc[mi][ni][r] + bv, 0.f));
                    } else {
                        if (n < 128) Of0[(size_t)m * 128 + n] = acc[mi][ni][r];
                        else         Obf[(size_t)m * 128 + (n - 128)] = f2bf(acc[mi][ni][r]);
                    }
                }
            }
        }
    }
}

// ---------------------------------------------------------------- launch
extern "C" void kernel_launch(void* const* d_in, const int* in_sizes, int n_in,
                              void* d_out, int out_size, void* d_ws, size_t ws_size,
                              hipStream_t stream) {
    const float* feat   = (const float*)d_in[0];
    const int*   src    = (const int*)d_in[1];
    const int*   dst    = (const int*)d_in[2];
    const float* W1s    = (const float*)d_in[3];
    const float* W1n    = (const float*)d_in[4];
    const float* b1     = (const float*)d_in[5];
    const float* W2s    = (const float*)d_in[6];
    const float* W2n    = (const float*)d_in[7];
    const float* b2     = (const float*)d_in[8];
    const float* Wp1    = (const float*)d_in[9];
    const float* bp1    = (const float*)d_in[10];
    const float* Wp2    = (const float*)d_in[11];
    const float* bp2    = (const float*)d_in[12];
    float* out = (float*)d_out;

    char* w = (char*)d_ws;
    size_t off = 0;
    auto alloc = [&](size_t bytes) { char* p = w + off; off += (bytes + 255) & ~(size_t)255; return p; };
    int*   deg    = (int*)alloc(N_NODES * 4);
    int*   rowptr = (int*)alloc((N_NODES + 1) * 4);
    int*   cursor = (int*)alloc(N_NODES * 4);
    int*   col    = (int*)alloc(N_EDGES * 4);
    float* dinv   = (float*)alloc(N_NODES * 4);
    int*   bsum   = (int*)alloc(64 * 4);
    int*   boff   = (int*)alloc(64 * 4);
    short* Abf    = (short*)alloc((size_t)N_NODES * 256 * 2);   // [feat|agg1] bf16
    short* W1T    = (short*)alloc((size_t)512 * 256 * 2);
    short* W2T    = (short*)alloc((size_t)256 * 512 * 2);
    short* h1bf   = (short*)alloc((size_t)N_NODES * 512 * 2);
    float* z      = (float*)alloc((size_t)N_NODES * 128 * 4);
    short* y1bf   = (short*)alloc((size_t)N_NODES * 128 * 2);

    hipMemsetAsync(deg, 0, N_NODES * 4, stream);
    k_deg<<<N_EDGES / 256, 256, 0, stream>>>(dst, deg);
    k_scan1<<<49, 1024, 0, stream>>>(deg, bsum, dinv);
    k_scan2<<<1, 64, 0, stream>>>(bsum, boff);
    k_scan3<<<49, 1024, 0, stream>>>(deg, boff, rowptr, cursor);
    k_fill<<<N_EDGES / 256, 256, 0, stream>>>(src, dst, cursor, col);
    k_cvt<<<7274, 256, 0, stream>>>(feat, W1s, W1n, W2s, W2n, Abf, W1T, W2T);
    k_agg<<<N_NODES / 4, 256, 0, stream>>>((const unsigned*)Abf, rowptr, col, dinv, (unsigned*)Abf);
    dim3 g1((N_NODES + 127) / 128, 4);
    k_gemm_mfma<256, 512, true><<<g1, 256, 0, stream>>>(Abf, W1T, b1, h1bf, nullptr);
    dim3 g2((N_NODES + 127) / 128, 2);
    k_gemm_mfma<512, 256, false><<<g2, 256, 0, stream>>>(h1bf, W2T, nullptr, y1bf, z);
    k_aggmlp<<<N_NODES / 4, 256, 0, stream>>>((const unsigned*)y1bf, rowptr, col, dinv, z, b2,
                                              Wp1, bp1, Wp2, bp2, out);
}

// Round 11
// 346.161 us; speedup vs baseline: 1.7676x; 1.1544x over previous
//
#include <hip/hip_runtime.h>
#include <hip/hip_bf16.h>

#define N_NODES 50000
#define N_EDGES 800000

typedef short  short8  __attribute__((ext_vector_type(8)));
typedef float  floatx4 __attribute__((ext_vector_type(4)));

__device__ __forceinline__ short f2bf(float f) {
    union { __hip_bfloat16 h; short s; } u;
    u.h = __float2bfloat16(f);
    return u.s;
}
__device__ __forceinline__ float2 upk(unsigned v) {
    union { float f; unsigned u; } a, b;
    a.u = v << 16; b.u = v & 0xffff0000u;
    return make_float2(a.f, b.f);
}
__device__ __forceinline__ unsigned packbf(float lo, float hi) {
    return ((unsigned)(unsigned short)f2bf(hi) << 16) | (unsigned short)f2bf(lo);
}

__device__ __forceinline__ void gld_lds16(const short* g, short* l) {
    __builtin_amdgcn_global_load_lds(
        (const __attribute__((address_space(1))) int*)g,
        (__attribute__((address_space(3))) int*)l, 16, 0, 0);
}

// ---------------------------------------------------------------- CSR build
__global__ void k_deg(const int* __restrict__ dst, int* __restrict__ deg) {
    int e = blockIdx.x * 256 + threadIdx.x;
    if (e < N_EDGES) atomicAdd(&deg[dst[e]], 1);
}

__global__ __launch_bounds__(1024) void k_scan1(const int* __restrict__ deg,
                                                int* __restrict__ bsum,
                                                float* __restrict__ dinv) {
    __shared__ int ws[16];
    int b = blockIdx.x, t = threadIdx.x, i = b * 1024 + t;
    int lane = t & 63, wid = t >> 6;
    int v = (i < N_NODES) ? deg[i] : 0;
    if (i < N_NODES) dinv[i] = 1.0f / fmaxf((float)v, 1.0f);
    int x = v;
    #pragma unroll
    for (int off = 1; off < 64; off <<= 1) x += __shfl_xor(x, off, 64);
    if (lane == 0) ws[wid] = x;
    __syncthreads();
    if (t == 0) {
        int s = 0;
        #pragma unroll
        for (int k = 0; k < 16; ++k) s += ws[k];
        bsum[b] = s;
    }
}

__global__ void k_scan2(const int* __restrict__ bsum, int* __restrict__ boff) {
    int lane = threadIdx.x;
    int v = (lane < 49) ? bsum[lane] : 0;
    int x = v;
    #pragma unroll
    for (int off = 1; off < 64; off <<= 1) {
        int y = __shfl_up(x, off, 64);
        if (lane >= off) x += y;
    }
    if (lane < 49) boff[lane] = x - v;
}

__global__ __launch_bounds__(1024) void k_scan3(const int* __restrict__ deg,
                                                const int* __restrict__ boff,
                                                int* __restrict__ rowptr,
                                                int* __restrict__ cursor) {
    __shared__ int ws[16];
    int b = blockIdx.x, t = threadIdx.x, i = b * 1024 + t;
    int lane = t & 63, wid = t >> 6;
    int v = (i < N_NODES) ? deg[i] : 0;
    int x = v;
    #pragma unroll
    for (int off = 1; off < 64; off <<= 1) {
        int y = __shfl_up(x, off, 64);
        if (lane >= off) x += y;
    }
    if (lane == 63) ws[wid] = x;
    __syncthreads();
    if (wid == 0) {
        int s = (lane < 16) ? ws[lane] : 0;
        #pragma unroll
        for (int off = 1; off < 16; off <<= 1) {
            int y = __shfl_up(s, off, 64);
            if (lane >= off) s += y;
        }
        if (lane < 16) ws[lane] = s;
    }
    __syncthreads();
    int waveOff = (wid == 0) ? 0 : ws[wid - 1];
    int incl = x + waveOff + boff[b];
    if (i < N_NODES) { rowptr[i + 1] = incl; cursor[i] = incl - v; }
    if (b == 0 && t == 0) rowptr[0] = 0;
}

__global__ void k_fill(const int* __restrict__ src, const int* __restrict__ dst,
                       int* __restrict__ cursor, int* __restrict__ col) {
    int e = blockIdx.x * 256 + threadIdx.x;
    if (e < N_EDGES) {
        int d = dst[e];
        int p = atomicAdd(&cursor[d], 1);
        col[p] = src[e];
    }
}

// ------------------------------------------- fused bf16 conversions
__global__ void k_cvt(const float* __restrict__ feat,
                      const float* __restrict__ W1s, const float* __restrict__ W1n,
                      const float* __restrict__ W2s, const float* __restrict__ W2n,
                      short* __restrict__ Abf, short* __restrict__ W1T,
                      short* __restrict__ W2T) {
    int bb = blockIdx.x, t = threadIdx.x;
    if (bb < 6250) {
        int idx = bb * 256 + t;
        if (idx >= N_NODES * 32) return;
        int n = idx >> 5, c = (idx & 31) * 4;
        float4 v = *(const float4*)(feat + (size_t)n * 128 + c);
        *(short4*)(Abf + (size_t)n * 256 + c) =
            make_short4(f2bf(v.x), f2bf(v.y), f2bf(v.z), f2bf(v.w));
    } else {
        int idx = (bb - 6250) * 256 + t;
        if (idx < 512 * 256) {
            int n = idx >> 8, k = idx & 255;
            float v = (k < 128) ? W1s[(size_t)k * 512 + n]
                                : W1n[(size_t)(k - 128) * 512 + n];
            W1T[idx] = f2bf(v);
        } else {
            int j = idx - 512 * 256;
            int n = j >> 9, k = j & 511;
            float v = (n < 128) ? W2s[(size_t)k * 128 + n]
                                : W2n[(size_t)k * 128 + (n - 128)];
            W2T[j] = f2bf(v);
        }
    }
}

// -------- wave-per-node gather core: scalar-base (readlane) row loads,
// 16-deep pipeline (proven best: rounds 6/8 ~63 us, ~1.5 TB/s fill).
template<int STRIDE>
__device__ __forceinline__ float2 wave_gather(
    const unsigned* __restrict__ U, const int* __restrict__ col,
    int s, int e, int lane) {
    float ax = 0.f, ay = 0.f;
    for (int base = s; base < e; base += 64) {
        int cnt = e - base; if (cnt > 64) cnt = 64;
        int myc = (base + lane < e) ? col[base + lane] : 0;
        int j = 0;
        for (; j + 16 <= cnt; j += 16) {
            unsigned v[16];
            #pragma unroll
            for (int u = 0; u < 16; ++u) {
                int c = __builtin_amdgcn_readlane(myc, j + u);
                v[u] = U[(size_t)c * STRIDE + lane];
            }
            #pragma unroll
            for (int u = 0; u < 16; ++u) {
                float2 f = upk(v[u]); ax += f.x; ay += f.y;
            }
        }
        for (; j + 8 <= cnt; j += 8) {
            unsigned v[8];
            #pragma unroll
            for (int u = 0; u < 8; ++u) {
                int c = __builtin_amdgcn_readlane(myc, j + u);
                v[u] = U[(size_t)c * STRIDE + lane];
            }
            #pragma unroll
            for (int u = 0; u < 8; ++u) {
                float2 f = upk(v[u]); ax += f.x; ay += f.y;
            }
        }
        if (j < cnt) {
            unsigned v[8];
            int m = cnt - j;
            #pragma unroll
            for (int u = 0; u < 8; ++u) {
                if (u < m) {
                    int c = __builtin_amdgcn_readlane(myc, j + u);
                    v[u] = U[(size_t)c * STRIDE + lane];
                }
            }
            #pragma unroll
            for (int u = 0; u < 8; ++u) {
                if (u < m) { float2 f = upk(v[u]); ax += f.x; ay += f.y; }
            }
        }
    }
    return make_float2(ax, ay);
}

// ---------------------------------------------- aggregation 1 (bf16 gather)
__global__ __launch_bounds__(256) void k_agg(
    const unsigned* __restrict__ Au, const int* __restrict__ rowptr,
    const int* __restrict__ col, const float* __restrict__ dinv,
    unsigned* __restrict__ Aw) {
    int t = threadIdx.x, lane = t & 63, w = t >> 6;
    int n = blockIdx.x * 4 + w;
    int s = rowptr[n], e = rowptr[n + 1];
    float2 a = wave_gather<128>(Au, col, s, e, lane);
    float dv = dinv[n];
    Aw[(size_t)n * 128 + 64 + lane] = packbf(a.x * dv, a.y * dv);
}

// --------------------- aggregation 2 + bias/relu + MLP + softmax (fused)
__global__ __launch_bounds__(256) void k_aggmlp(
    const unsigned* __restrict__ Yu, const int* __restrict__ rowptr,
    const int* __restrict__ col, const float* __restrict__ dinv,
    const float* __restrict__ z, const float* __restrict__ b2,
    const float* __restrict__ Wp1, const float* __restrict__ bp1,
    const float* __restrict__ Wp2, const float* __restrict__ bp2,
    float* __restrict__ out) {
    __shared__ float h2sh[4][128];
    __shared__ float xsh[4][32];
    int t = threadIdx.x, lane = t & 63, w = t >> 6;
    int n = blockIdx.x * 4 + w;
    int s = rowptr[n], e = rowptr[n + 1];
    float2 a = wave_gather<64>(Yu, col, s, e, lane);
    float dv = dinv[n];
    float2 zv = *(const float2*)(z + (size_t)n * 128 + 2 * lane);
    float2 bb = *(const float2*)(b2 + 2 * lane);
    h2sh[w][2 * lane]     = fmaxf(zv.x + a.x * dv + bb.x, 0.f);
    h2sh[w][2 * lane + 1] = fmaxf(zv.y + a.y * dv + bb.y, 0.f);
    // intra-wave consumers only: no barrier needed (wave lockstep)
    int j = lane & 31, half = lane >> 5;
    float p = 0.f;
    #pragma unroll
    for (int k2 = 0; k2 < 64; ++k2) {
        int k = half * 64 + k2;
        p += h2sh[w][k] * Wp1[k * 32 + j];
    }
    p += __shfl_xor(p, 32, 64);
    if (half == 0) xsh[w][j] = fmaxf(p + bp1[j], 0.f);
    if (lane < 8) {
        float lg = bp2[lane];
        #pragma unroll
        for (int jj = 0; jj < 32; ++jj)
            lg += xsh[w][jj] * Wp2[jj * 8 + lane];
        float mx = lg;
        mx = fmaxf(mx, __shfl_xor(mx, 1, 64));
        mx = fmaxf(mx, __shfl_xor(mx, 2, 64));
        mx = fmaxf(mx, __shfl_xor(mx, 4, 64));
        float ev = expf(lg - mx);
        float sm = ev;
        sm += __shfl_xor(sm, 1, 64);
        sm += __shfl_xor(sm, 2, 64);
        sm += __shfl_xor(sm, 4, 64);
        out[(size_t)n * 8 + lane] = ev / sm;
    }
}

// ------------------------------------------------------- MFMA bf16 GEMM
template<int K, int N, bool EPI1>
__global__ __launch_bounds__(256) void k_gemm_mfma(
    const short* __restrict__ A, const short* __restrict__ BT,
    const float* __restrict__ bias, short* __restrict__ Obf,
    float* __restrict__ Of0) {
    __shared__ short sA[128 * 32];
    __shared__ short sB[128 * 32];
    const int t = threadIdx.x;
    const int lane = t & 63;
    const int w = t >> 6;
    const int mBase = blockIdx.x * 128;
    const int nBase = blockIdx.y * 128;
    const int mOff = (w & 1) * 64;
    const int nOff = (w >> 1) * 64;

    floatx4 zero4 = {0.f, 0.f, 0.f, 0.f};
    floatx4 acc[4][4];
    #pragma unroll
    for (int i = 0; i < 4; ++i)
        #pragma unroll
        for (int j = 0; j < 4; ++j) acc[i][j] = zero4;

    const int rL = lane >> 2;
    const int cg = (((lane & 3) ^ ((lane >> 3) & 3))) * 8;
    const int rA = w * 32 + rL;
    const long gA0 = (long)min(mBase + rA,      N_NODES - 1) * K + cg;
    const long gA1 = (long)min(mBase + rA + 16, N_NODES - 1) * K + cg;
    const long gB0 = (long)(nBase + rA)      * K + cg;
    const long gB1 = (long)(nBase + rA + 16) * K + cg;
    short* lA0 = sA + (w * 32) * 32;
    short* lA1 = sA + (w * 32 + 16) * 32;
    short* lB0 = sB + (w * 32) * 32;
    short* lB1 = sB + (w * 32 + 16) * 32;

    const int fr = lane & 15;
    const int csel = (((lane >> 4) ^ ((lane >> 1) & 3))) * 8;

    for (int kt = 0; kt < K / 32; ++kt) {
        const int k0 = kt * 32;
        __syncthreads();
        gld_lds16(A + gA0 + k0, lA0);
        gld_lds16(A + gA1 + k0, lA1);
        gld_lds16(BT + gB0 + k0, lB0);
        gld_lds16(BT + gB1 + k0, lB1);
        __syncthreads();
        short8 af[4], bf[4];
        #pragma unroll
        for (int i = 0; i < 4; ++i) {
            af[i] = *(const short8*)(sA + (mOff + i * 16 + fr) * 32 + csel);
            bf[i] = *(const short8*)(sB + (nOff + i * 16 + fr) * 32 + csel);
        }
        #pragma unroll
        for (int mi = 0; mi < 4; ++mi)
            #pragma unroll
            for (int ni = 0; ni < 4; ++ni)
                acc[mi][ni] = __builtin_amdgcn_mfma_f32_16x16x32_bf16(
                    af[mi], bf[ni], acc[mi][ni], 0, 0, 0);
    }

    const int cn = lane & 15;
    const int cm = (lane >> 4) * 4;
    #pragma unroll
    for (int ni = 0; ni < 4; ++ni) {
        const int n = nBase + nOff + ni * 16 + cn;
        float bv = 0.f;
        if constexpr (EPI1) bv = bias[n];
        #pragma unroll
        for (int mi = 0; mi < 4; ++mi) {
            #pragma unroll
            for (int r = 0; r < 4; ++r) {
                const int m = mBase + mOff + mi * 16 + cm + r;
                if (m < N_NODES) {
                    if constexpr (EPI1) {
                        Obf[(size_t)m * N + n] = f2bf(fmaxf(acc[mi][ni][r] + bv, 0.f));
                    } else {
                        if (n < 128) Of0[(size_t)m * 128 + n] = acc[mi][ni][r];
                        else         Obf[(size_t)m * 128 + (n - 128)] = f2bf(acc[mi][ni][r]);
                    }
                }
            }
        }
    }
}

// ---------------------------------------------------------------- launch
extern "C" void kernel_launch(void* const* d_in, const int* in_sizes, int n_in,
                              void* d_out, int out_size, void* d_ws, size_t ws_size,
                              hipStream_t stream) {
    const float* feat   = (const float*)d_in[0];
    const int*   src    = (const int*)d_in[1];
    const int*   dst    = (const int*)d_in[2];
    const float* W1s    = (const float*)d_in[3];
    const float* W1n    = (const float*)d_in[4];
    const float* b1     = (const float*)d_in[5];
    const float* W2s    = (const float*)d_in[6];
    const float* W2n    = (const float*)d_in[7];
    const float* b2     = (const float*)d_in[8];
    const float* Wp1    = (const float*)d_in[9];
    const float* bp1    = (const float*)d_in[10];
    const float* Wp2    = (const float*)d_in[11];
    const float* bp2    = (const float*)d_in[12];
    float* out = (float*)d_out;

    char* w = (char*)d_ws;
    size_t off = 0;
    auto alloc = [&](size_t bytes) { char* p = w + off; off += (bytes + 255) & ~(size_t)255; return p; };
    int*   deg    = (int*)alloc(N_NODES * 4);
    int*   rowptr = (int*)alloc((N_NODES + 1) * 4);
    int*   cursor = (int*)alloc(N_NODES * 4);
    int*   col    = (int*)alloc(N_EDGES * 4);
    float* dinv   = (float*)alloc(N_NODES * 4);
    int*   bsum   = (int*)alloc(64 * 4);
    int*   boff   = (int*)alloc(64 * 4);
    short* Abf    = (short*)alloc((size_t)N_NODES * 256 * 2);   // [feat|agg1] bf16
    short* W1T    = (short*)alloc((size_t)512 * 256 * 2);
    short* W2T    = (short*)alloc((size_t)256 * 512 * 2);
    short* h1bf   = (short*)alloc((size_t)N_NODES * 512 * 2);
    float* z      = (float*)alloc((size_t)N_NODES * 128 * 4);
    short* y1bf   = (short*)alloc((size_t)N_NODES * 128 * 2);

    hipMemsetAsync(deg, 0, N_NODES * 4, stream);
    k_deg<<<N_EDGES / 256, 256, 0, stream>>>(dst, deg);
    k_scan1<<<49, 1024, 0, stream>>>(deg, bsum, dinv);
    k_scan2<<<1, 64, 0, stream>>>(bsum, boff);
    k_scan3<<<49, 1024, 0, stream>>>(deg, boff, rowptr, cursor);
    k_fill<<<N_EDGES / 256, 256, 0, stream>>>(src, dst, cursor, col);
    k_cvt<<<7274, 256, 0, stream>>>(feat, W1s, W1n, W2s, W2n, Abf, W1T, W2T);
    k_agg<<<N_NODES / 4, 256, 0, stream>>>((const unsigned*)Abf, rowptr, col, dinv, (unsigned*)Abf);
    dim3 g1((N_NODES + 127) / 128, 4);
    k_gemm_mfma<256, 512, true><<<g1, 256, 0, stream>>>(Abf, W1T, b1, h1bf, nullptr);
    dim3 g2((N_NODES + 127) / 128, 2);
    k_gemm_mfma<512, 256, false><<<g2, 256, 0, stream>>>(h1bf, W2T, nullptr, y1bf, z);
    k_aggmlp<<<N_NODES / 4, 256, 0, stream>>>((const unsigned*)y1bf, rowptr, col, dinv, z, b2,
                                              Wp1, bp1, Wp2, bp2, out);
}

// Round 12
// 337.767 us; speedup vs baseline: 1.8115x; 1.0249x over previous
//
#include <hip/hip_runtime.h>
#include <hip/hip_bf16.h>

#define N_NODES 50000
#define N_EDGES 800000

typedef short  short8  __attribute__((ext_vector_type(8)));
typedef float  floatx4 __attribute__((ext_vector_type(4)));

__device__ __forceinline__ short f2bf(float f) {
    union { __hip_bfloat16 h; short s; } u;
    u.h = __float2bfloat16(f);
    return u.s;
}
__device__ __forceinline__ float2 upk(unsigned v) {
    union { float f; unsigned u; } a, b;
    a.u = v << 16; b.u = v & 0xffff0000u;
    return make_float2(a.f, b.f);
}
__device__ __forceinline__ unsigned packbf(float lo, float hi) {
    return ((unsigned)(unsigned short)f2bf(hi) << 16) | (unsigned short)f2bf(lo);
}

__device__ __forceinline__ void gld_lds16(const short* g, short* l) {
    __builtin_amdgcn_global_load_lds(
        (const __attribute__((address_space(1))) int*)g,
        (__attribute__((address_space(3))) int*)l, 16, 0, 0);
}

// ---------------------------------------------------------------- CSR build
__global__ void k_deg(const int* __restrict__ dst, int* __restrict__ deg) {
    int e = blockIdx.x * 256 + threadIdx.x;
    if (e < N_EDGES) atomicAdd(&deg[dst[e]], 1);
}

__global__ __launch_bounds__(1024) void k_scan1(const int* __restrict__ deg,
                                                int* __restrict__ bsum,
                                                float* __restrict__ dinv) {
    __shared__ int ws[16];
    int b = blockIdx.x, t = threadIdx.x, i = b * 1024 + t;
    int lane = t & 63, wid = t >> 6;
    int v = (i < N_NODES) ? deg[i] : 0;
    if (i < N_NODES) dinv[i] = 1.0f / fmaxf((float)v, 1.0f);
    int x = v;
    #pragma unroll
    for (int off = 1; off < 64; off <<= 1) x += __shfl_xor(x, off, 64);
    if (lane == 0) ws[wid] = x;
    __syncthreads();
    if (t == 0) {
        int s = 0;
        #pragma unroll
        for (int k = 0; k < 16; ++k) s += ws[k];
        bsum[b] = s;
    }
}

__global__ void k_scan2(const int* __restrict__ bsum, int* __restrict__ boff) {
    int lane = threadIdx.x;
    int v = (lane < 49) ? bsum[lane] : 0;
    int x = v;
    #pragma unroll
    for (int off = 1; off < 64; off <<= 1) {
        int y = __shfl_up(x, off, 64);
        if (lane >= off) x += y;
    }
    if (lane < 49) boff[lane] = x - v;
}

__global__ __launch_bounds__(1024) void k_scan3(const int* __restrict__ deg,
                                                const int* __restrict__ boff,
                                                int* __restrict__ rowptr,
                                                int* __restrict__ cursor) {
    __shared__ int ws[16];
    int b = blockIdx.x, t = threadIdx.x, i = b * 1024 + t;
    int lane = t & 63, wid = t >> 6;
    int v = (i < N_NODES) ? deg[i] : 0;
    int x = v;
    #pragma unroll
    for (int off = 1; off < 64; off <<= 1) {
        int y = __shfl_up(x, off, 64);
        if (lane >= off) x += y;
    }
    if (lane == 63) ws[wid] = x;
    __syncthreads();
    if (wid == 0) {
        int s = (lane < 16) ? ws[lane] : 0;
        #pragma unroll
        for (int off = 1; off < 16; off <<= 1) {
            int y = __shfl_up(s, off, 64);
            if (lane >= off) s += y;
        }
        if (lane < 16) ws[lane] = s;
    }
    __syncthreads();
    int waveOff = (wid == 0) ? 0 : ws[wid - 1];
    int incl = x + waveOff + boff[b];
    if (i < N_NODES) { rowptr[i + 1] = incl; cursor[i] = incl - v; }
    if (b == 0 && t == 0) rowptr[0] = 0;
}

__global__ void k_fill(const int* __restrict__ src, const int* __restrict__ dst,
                       int* __restrict__ cursor, int* __restrict__ col) {
    int e = blockIdx.x * 256 + threadIdx.x;
    if (e < N_EDGES) {
        int d = dst[e];
        int p = atomicAdd(&cursor[d], 1);
        col[p] = src[e];
    }
}

// ------------------------------------------- fused bf16 conversions
__global__ void k_cvt(const float* __restrict__ feat,
                      const float* __restrict__ W1s, const float* __restrict__ W1n,
                      const float* __restrict__ W2s, const float* __restrict__ W2n,
                      short* __restrict__ Abf, short* __restrict__ W1T,
                      short* __restrict__ W2T) {
    int bb = blockIdx.x, t = threadIdx.x;
    if (bb < 6250) {
        int idx = bb * 256 + t;
        if (idx >= N_NODES * 32) return;
        int n = idx >> 5, c = (idx & 31) * 4;
        float4 v = *(const float4*)(feat + (size_t)n * 128 + c);
        *(short4*)(Abf + (size_t)n * 256 + c) =
            make_short4(f2bf(v.x), f2bf(v.y), f2bf(v.z), f2bf(v.w));
    } else {
        int idx = (bb - 6250) * 256 + t;
        if (idx < 512 * 256) {
            int n = idx >> 8, k = idx & 255;
            float v = (k < 128) ? W1s[(size_t)k * 512 + n]
                                : W1n[(size_t)(k - 128) * 512 + n];
            W1T[idx] = f2bf(v);
        } else {
            int j = idx - 512 * 256;
            int n = j >> 9, k = j & 511;
            float v = (n < 128) ? W2s[(size_t)k * 128 + n]
                                : W2n[(size_t)k * 128 + (n - 128)];
            W2T[j] = f2bf(v);
        }
    }
}

// -------- wave-per-node gather core: scalar-base (readlane) row loads,
// 16-deep pipeline (proven best: ~63 us, ~1.5 TB/s random-row fill ceiling).
template<int STRIDE>
__device__ __forceinline__ float2 wave_gather(
    const unsigned* __restrict__ U, const int* __restrict__ col,
    int s, int e, int lane) {
    float ax = 0.f, ay = 0.f;
    for (int base = s; base < e; base += 64) {
        int cnt = e - base; if (cnt > 64) cnt = 64;
        int myc = (base + lane < e) ? col[base + lane] : 0;
        int j = 0;
        for (; j + 16 <= cnt; j += 16) {
            unsigned v[16];
            #pragma unroll
            for (int u = 0; u < 16; ++u) {
                int c = __builtin_amdgcn_readlane(myc, j + u);
                v[u] = U[(size_t)c * STRIDE + lane];
            }
            #pragma unroll
            for (int u = 0; u < 16; ++u) {
                float2 f = upk(v[u]); ax += f.x; ay += f.y;
            }
        }
        for (; j + 8 <= cnt; j += 8) {
            unsigned v[8];
            #pragma unroll
            for (int u = 0; u < 8; ++u) {
                int c = __builtin_amdgcn_readlane(myc, j + u);
                v[u] = U[(size_t)c * STRIDE + lane];
            }
            #pragma unroll
            for (int u = 0; u < 8; ++u) {
                float2 f = upk(v[u]); ax += f.x; ay += f.y;
            }
        }
        if (j < cnt) {
            unsigned v[8];
            int m = cnt - j;
            #pragma unroll
            for (int u = 0; u < 8; ++u) {
                if (u < m) {
                    int c = __builtin_amdgcn_readlane(myc, j + u);
                    v[u] = U[(size_t)c * STRIDE + lane];
                }
            }
            #pragma unroll
            for (int u = 0; u < 8; ++u) {
                if (u < m) { float2 f = upk(v[u]); ax += f.x; ay += f.y; }
            }
        }
    }
    return make_float2(ax, ay);
}

// ---------------------------------------------- aggregation 1 (bf16 gather)
__global__ __launch_bounds__(256) void k_agg(
    const unsigned* __restrict__ Au, const int* __restrict__ rowptr,
    const int* __restrict__ col, const float* __restrict__ dinv,
    unsigned* __restrict__ Aw) {
    int t = threadIdx.x, lane = t & 63, w = t >> 6;
    int n = blockIdx.x * 4 + w;
    int s = rowptr[n], e = rowptr[n + 1];
    float2 a = wave_gather<128>(Au, col, s, e, lane);
    float dv = dinv[n];
    Aw[(size_t)n * 128 + 64 + lane] = packbf(a.x * dv, a.y * dv);
}

// --------------------- aggregation 2 + bias/relu + MLP + softmax (fused)
__global__ __launch_bounds__(256) void k_aggmlp(
    const unsigned* __restrict__ Yu, const int* __restrict__ rowptr,
    const int* __restrict__ col, const float* __restrict__ dinv,
    const float* __restrict__ z, const float* __restrict__ b2,
    const float* __restrict__ Wp1, const float* __restrict__ bp1,
    const float* __restrict__ Wp2, const float* __restrict__ bp2,
    float* __restrict__ out) {
    __shared__ float h2sh[4][128];
    __shared__ float xsh[4][32];
    int t = threadIdx.x, lane = t & 63, w = t >> 6;
    int n = blockIdx.x * 4 + w;
    int s = rowptr[n], e = rowptr[n + 1];
    float2 a = wave_gather<64>(Yu, col, s, e, lane);
    float dv = dinv[n];
    float2 zv = *(const float2*)(z + (size_t)n * 128 + 2 * lane);
    float2 bb = *(const float2*)(b2 + 2 * lane);
    h2sh[w][2 * lane]     = fmaxf(zv.x + a.x * dv + bb.x, 0.f);
    h2sh[w][2 * lane + 1] = fmaxf(zv.y + a.y * dv + bb.y, 0.f);
    // intra-wave consumers only: no barrier needed (wave lockstep)
    int j = lane & 31, half = lane >> 5;
    float p = 0.f;
    #pragma unroll
    for (int k2 = 0; k2 < 64; ++k2) {
        int k = half * 64 + k2;
        p += h2sh[w][k] * Wp1[k * 32 + j];
    }
    p += __shfl_xor(p, 32, 64);
    if (half == 0) xsh[w][j] = fmaxf(p + bp1[j], 0.f);
    if (lane < 8) {
        float lg = bp2[lane];
        #pragma unroll
        for (int jj = 0; jj < 32; ++jj)
            lg += xsh[w][jj] * Wp2[jj * 8 + lane];
        float mx = lg;
        mx = fmaxf(mx, __shfl_xor(mx, 1, 64));
        mx = fmaxf(mx, __shfl_xor(mx, 2, 64));
        mx = fmaxf(mx, __shfl_xor(mx, 4, 64));
        float ev = expf(lg - mx);
        float sm = ev;
        sm += __shfl_xor(sm, 1, 64);
        sm += __shfl_xor(sm, 2, 64);
        sm += __shfl_xor(sm, 4, 64);
        out[(size_t)n * 8 + lane] = ev / sm;
    }
}

// ------------------------------------------------------- MFMA bf16 GEMM
// Epilogue for bf16 outputs staged through LDS (reusing sA/sB) so global
// stores are row-contiguous 16B vectors -> full-line writes, no RFO fetch.
template<int K, int N, bool EPI1>
__global__ __launch_bounds__(256) void k_gemm_mfma(
    const short* __restrict__ A, const short* __restrict__ BT,
    const float* __restrict__ bias, short* __restrict__ Obf,
    float* __restrict__ Of0) {
    __shared__ short smem[2 * 128 * 32];
    short* sA = smem;
    short* sB = smem + 128 * 32;
    short* sOut = smem;                 // epilogue reuse: 64 x 128 bf16
    const int t = threadIdx.x;
    const int lane = t & 63;
    const int w = t >> 6;
    const int mBase = blockIdx.x * 128;
    const int nBase = blockIdx.y * 128;
    const int mOff = (w & 1) * 64;
    const int nOff = (w >> 1) * 64;

    floatx4 zero4 = {0.f, 0.f, 0.f, 0.f};
    floatx4 acc[4][4];
    #pragma unroll
    for (int i = 0; i < 4; ++i)
        #pragma unroll
        for (int j = 0; j < 4; ++j) acc[i][j] = zero4;

    const int rL = lane >> 2;
    const int cg = (((lane & 3) ^ ((lane >> 3) & 3))) * 8;
    const int rA = w * 32 + rL;
    const long gA0 = (long)min(mBase + rA,      N_NODES - 1) * K + cg;
    const long gA1 = (long)min(mBase + rA + 16, N_NODES - 1) * K + cg;
    const long gB0 = (long)(nBase + rA)      * K + cg;
    const long gB1 = (long)(nBase + rA + 16) * K + cg;
    short* lA0 = sA + (w * 32) * 32;
    short* lA1 = sA + (w * 32 + 16) * 32;
    short* lB0 = sB + (w * 32) * 32;
    short* lB1 = sB + (w * 32 + 16) * 32;

    const int fr = lane & 15;
    const int csel = (((lane >> 4) ^ ((lane >> 1) & 3))) * 8;

    for (int kt = 0; kt < K / 32; ++kt) {
        const int k0 = kt * 32;
        __syncthreads();
        gld_lds16(A + gA0 + k0, lA0);
        gld_lds16(A + gA1 + k0, lA1);
        gld_lds16(BT + gB0 + k0, lB0);
        gld_lds16(BT + gB1 + k0, lB1);
        __syncthreads();
        short8 af[4], bf[4];
        #pragma unroll
        for (int i = 0; i < 4; ++i) {
            af[i] = *(const short8*)(sA + (mOff + i * 16 + fr) * 32 + csel);
            bf[i] = *(const short8*)(sB + (nOff + i * 16 + fr) * 32 + csel);
        }
        #pragma unroll
        for (int mi = 0; mi < 4; ++mi)
            #pragma unroll
            for (int ni = 0; ni < 4; ++ni)
                acc[mi][ni] = __builtin_amdgcn_mfma_f32_16x16x32_bf16(
                    af[mi], bf[ni], acc[mi][ni], 0, 0, 0);
    }

    // D frag layout: col = lane&15, row = (lane>>4)*4 + reg
    const int cn = lane & 15;
    const int cm = (lane >> 4) * 4;

    if (!EPI1 && nBase < 128) {
        // z output (fp32): direct stores, 16-lane x 4B = 64B contiguous bursts
        #pragma unroll
        for (int ni = 0; ni < 4; ++ni) {
            const int n = nOff + ni * 16 + cn;
            #pragma unroll
            for (int mi = 0; mi < 4; ++mi) {
                #pragma unroll
                for (int r = 0; r < 4; ++r) {
                    const int m = mBase + mOff + mi * 16 + cm + r;
                    if (m < N_NODES) Of0[(size_t)m * 128 + n] = acc[mi][ni][r];
                }
            }
        }
        return;
    }

    // bf16 outputs (h1bf / y1bf): stage 64-row halves in LDS, then store
    // 32 contiguous shorts per thread (4 x b128) -> full-line writes.
    float bv[4];
    #pragma unroll
    for (int ni = 0; ni < 4; ++ni)
        bv[ni] = EPI1 ? bias[nBase + nOff + ni * 16 + cn] : 0.f;
    const int myh = mOff >> 6;
    const int ldc = EPI1 ? N : 128;
    const int cbase = EPI1 ? nBase : 0;
    for (int h = 0; h < 2; ++h) {
        __syncthreads();
        if (myh == h) {
            #pragma unroll
            for (int mi = 0; mi < 4; ++mi)
                #pragma unroll
                for (int ni = 0; ni < 4; ++ni)
                    #pragma unroll
                    for (int r = 0; r < 4; ++r) {
                        int mrow = mi * 16 + cm + r;
                        int nloc = nOff + ni * 16 + cn;
                        float v = acc[mi][ni][r];
                        if (EPI1) v = fmaxf(v + bv[ni], 0.f);
                        sOut[mrow * 128 + nloc] = f2bf(v);
                    }
        }
        __syncthreads();
        int r0 = t >> 2, c0 = (t & 3) * 32;
        int m = mBase + h * 64 + r0;
        if (m < N_NODES) {
            const short* sp = sOut + r0 * 128 + c0;
            short* gp = Obf + (size_t)m * ldc + cbase + c0;
            #pragma unroll
            for (int q = 0; q < 4; ++q)
                *(short8*)(gp + q * 8) = *(const short8*)(sp + q * 8);
        }
    }
}

// ---------------------------------------------------------------- launch
extern "C" void kernel_launch(void* const* d_in, const int* in_sizes, int n_in,
                              void* d_out, int out_size, void* d_ws, size_t ws_size,
                              hipStream_t stream) {
    const float* feat   = (const float*)d_in[0];
    const int*   src    = (const int*)d_in[1];
    const int*   dst    = (const int*)d_in[2];
    const float* W1s    = (const float*)d_in[3];
    const float* W1n    = (const float*)d_in[4];
    const float* b1     = (const float*)d_in[5];
    const float* W2s    = (const float*)d_in[6];
    const float* W2n    = (const float*)d_in[7];
    const float* b2     = (const float*)d_in[8];
    const float* Wp1    = (const float*)d_in[9];
    const float* bp1    = (const float*)d_in[10];
    const float* Wp2    = (const float*)d_in[11];
    const float* bp2    = (const float*)d_in[12];
    float* out = (float*)d_out;

    char* w = (char*)d_ws;
    size_t off = 0;
    auto alloc = [&](size_t bytes) { char* p = w + off; off += (bytes + 255) & ~(size_t)255; return p; };
    int*   deg    = (int*)alloc(N_NODES * 4);
    int*   rowptr = (int*)alloc((N_NODES + 1) * 4);
    int*   cursor = (int*)alloc(N_NODES * 4);
    int*   col    = (int*)alloc(N_EDGES * 4);
    float* dinv   = (float*)alloc(N_NODES * 4);
    int*   bsum   = (int*)alloc(64 * 4);
    int*   boff   = (int*)alloc(64 * 4);
    short* Abf    = (short*)alloc((size_t)N_NODES * 256 * 2);   // [feat|agg1] bf16
    short* W1T    = (short*)alloc((size_t)512 * 256 * 2);
    short* W2T    = (short*)alloc((size_t)256 * 512 * 2);
    short* h1bf   = (short*)alloc((size_t)N_NODES * 512 * 2);
    float* z      = (float*)alloc((size_t)N_NODES * 128 * 4);
    short* y1bf   = (short*)alloc((size_t)N_NODES * 128 * 2);

    hipMemsetAsync(deg, 0, N_NODES * 4, stream);
    k_deg<<<N_EDGES / 256, 256, 0, stream>>>(dst, deg);
    k_scan1<<<49, 1024, 0, stream>>>(deg, bsum, dinv);
    k_scan2<<<1, 64, 0, stream>>>(bsum, boff);
    k_scan3<<<49, 1024, 0, stream>>>(deg, boff, rowptr, cursor);
    k_fill<<<N_EDGES / 256, 256, 0, stream>>>(src, dst, cursor, col);
    k_cvt<<<7274, 256, 0, stream>>>(feat, W1s, W1n, W2s, W2n, Abf, W1T, W2T);
    k_agg<<<N_NODES / 4, 256, 0, stream>>>((const unsigned*)Abf, rowptr, col, dinv, (unsigned*)Abf);
    dim3 g1((N_NODES + 127) / 128, 4);
    k_gemm_mfma<256, 512, true><<<g1, 256, 0, stream>>>(Abf, W1T, b1, h1bf, nullptr);
    dim3 g2((N_NODES + 127) / 128, 2);
    k_gemm_mfma<512, 256, false><<<g2, 256, 0, stream>>>(h1bf, W2T, nullptr, y1bf, z);
    k_aggmlp<<<N_NODES / 4, 256, 0, stream>>>((const unsigned*)y1bf, rowptr, col, dinv, z, b2,
                                              Wp1, bp1, Wp2, bp2, out);
}